// Round 9
// baseline (272.585 us; speedup 1.0000x reference)
//
#include <hip/hip_runtime.h>
#include <hip/hip_fp16.h>

// ---------------------------------------------------------------------------
// PMLP forward: 3 x (GEMM -> symmetric-norm propagate -> bias[+relu])
// N=50000 nodes, E=800000 edges, dims 128->128->128->64, fp32 in/out.
// R2..R11: CSR gather, fp16 MFMA GEMM. R14: barrier-free fused gather+GEMM.
// R15/R16/R18/R19/R20 REVERTED: concurrency/batch-width/unfuse experiments --
//      gather is throughput-saturated on the random L2-miss path; only
//      traffic reduction moves it.
// R17: wave-staged LDS edata, 4-wide (248.2us).
// R21: bp [b_quad][bin] + staged k_gather_out (241.2us).
// R22 (this): CSR build via GLOBAL ATOMICS, dropping the atomic-free
//      machinery. Edge order within a node's list is irrelevant for a sum,
//      so: k_count (deg[c]++ atomics) -> light 3-stage scan of deg ->
//      k_fill (pos = offs[c] + atomicAdd(cur[c])). Deletes k_hist, k_merge,
//      partial (12.8MB W + 12.8MB R), bp (12.8MB W + random R), rank (0.8MB
//      x2) -- ~40MB traffic and 1 launch. deg/cur zeroing folded into
//      k_cvtw. 1.6M int atomics over 50K addrs = L2-rate, few us.
//      Gather/GEMM kernels unchanged from R21.
// ---------------------------------------------------------------------------

#define NBINS 50000
#define EDCAP 1024      // LDS edge-slice capacity per k_gg wave (avg ~272)
#define EDCAP2 512      // LDS edge-slice capacity per k_gather_out wave
#define SLOT 51200      // workspace slot stride (ints)

typedef unsigned int uint32;
typedef unsigned char uint8;
typedef _Float16 half8 __attribute__((ext_vector_type(8)));
typedef float floatx4 __attribute__((ext_vector_type(4)));

// ---------------- weight convert + workspace zero ----------------
__global__ __launch_bounds__(256) void k_cvtw(const float* __restrict__ w0,
                                              const float* __restrict__ w1,
                                              const float* __restrict__ w2,
                                              __half* __restrict__ dst,
                                              int* __restrict__ zbuf, int zn) {
    const int tid = blockIdx.x * 256 + threadIdx.x;   // 0..10239
    for (int j = tid; j < zn; j += 40 * 256) zbuf[j] = 0;
    if (tid >= 10240) return;
    const float* s;
    int off;
    if (tid < 4096)      { s = w0; off = tid; }
    else if (tid < 8192) { s = w1; off = tid - 4096; }
    else                 { s = w2; off = tid - 8192; }
    float4 v = reinterpret_cast<const float4*>(s)[off];
    __half2 h0 = __floats2half2_rn(v.x, v.y);
    __half2 h1 = __floats2half2_rn(v.z, v.w);
    uint2 o;
    o.x = *reinterpret_cast<uint32*>(&h0);
    o.y = *reinterpret_cast<uint32*>(&h1);
    reinterpret_cast<uint2*>(dst)[tid] = o;
}

// ---------------- CSR build (global atomics) ----------------
__global__ __launch_bounds__(256) void k_count(const int* __restrict__ ei,
                                               int* __restrict__ deg, int E) {
    int e = blockIdx.x * 256 + threadIdx.x;
    if (e < E) atomicAdd(&deg[ei[E + e]], 1);
}

// per-256-bin block scan of deg -> local-exclusive offs, block total, dinv
__global__ __launch_bounds__(256) void k_scan_blk(const int* __restrict__ deg,
                                                  int* __restrict__ bsum,
                                                  int* __restrict__ offs,
                                                  float* __restrict__ dinv, int n) {
    __shared__ int wsums[5];
    const int tid = threadIdx.x;
    const int bin = blockIdx.x * 256 + tid;
    const int lane = tid & 63;
    const int wid = tid >> 6;
    int v = 0;
    if (bin < n) {
        v = deg[bin];
        dinv[bin] = rsqrtf((float)v + 1.0f);
    }
    int s = v;
#pragma unroll
    for (int off = 1; off < 64; off <<= 1) {
        int t = __shfl_up(s, off);
        if (lane >= off) s += t;
    }
    if (lane == 63) wsums[wid] = s;
    __syncthreads();
    if (tid == 0) {
        int a = 0;
        for (int w = 0; w < 4; ++w) { int t = wsums[w]; wsums[w] = a; a += t; }
        wsums[4] = a;
    }
    __syncthreads();
    if (bin < n) offs[bin] = wsums[wid] + s - v;
    if (tid == 255) bsum[blockIdx.x] = wsums[4];
}

__global__ __launch_bounds__(256) void k_scan_top(const int* __restrict__ bsum,
                                                  int* __restrict__ bpre,
                                                  int* __restrict__ offs,
                                                  int nblk, int n) {
    __shared__ int wsums[5];
    const int tid = threadIdx.x;
    const int lane = tid & 63;
    const int wid = tid >> 6;
    int v = (tid < nblk) ? bsum[tid] : 0;
    int s = v;
#pragma unroll
    for (int off = 1; off < 64; off <<= 1) {
        int t = __shfl_up(s, off);
        if (lane >= off) s += t;
    }
    if (lane == 63) wsums[wid] = s;
    __syncthreads();
    if (tid == 0) {
        int a = 0;
        for (int w = 0; w < 4; ++w) { int t = wsums[w]; wsums[w] = a; a += t; }
        wsums[4] = a;
    }
    __syncthreads();
    if (tid < nblk) bpre[tid] = wsums[wid] + s - v;
    if (tid == 0) offs[n] = wsums[4];
}

__global__ __launch_bounds__(256) void k_add(int* __restrict__ offs,
                                             const int* __restrict__ bpre, int n) {
    int bin = blockIdx.x * 256 + threadIdx.x;
    if (bin < n) offs[bin] += bpre[blockIdx.x];
}

__global__ __launch_bounds__(256) void k_fill(const int* __restrict__ ei,
                                              const int* __restrict__ offs,
                                              int* __restrict__ cur,
                                              const float* __restrict__ dinv,
                                              uint32* __restrict__ edata, int E) {
    int e = blockIdx.x * 256 + threadIdx.x;
    if (e >= E) return;
    int r = ei[e];
    int c = ei[E + e];
    int pos = offs[c] + atomicAdd(&cur[c], 1);
    __half h = __float2half(dinv[r] * dinv[c]);
    unsigned short hb = *reinterpret_cast<unsigned short*>(&h);
    edata[pos] = (uint32)(unsigned short)r | ((uint32)hb << 16);
}

// ---------------- gather helpers ----------------
struct f8 { float4 lo, hi; };
__device__ inline f8 cvt8(uint4 u) {
    __half2* h = reinterpret_cast<__half2*>(&u);
    float2 a = __half22float2(h[0]);
    float2 b = __half22float2(h[1]);
    float2 c = __half22float2(h[2]);
    float2 d = __half22float2(h[3]);
    f8 r;
    r.lo = make_float4(a.x, a.y, b.x, b.y);
    r.hi = make_float4(c.x, c.y, d.x, d.y);
    return r;
}
__device__ inline void fma8(f8& acc, float s, const f8& v) {
    acc.lo.x += s * v.lo.x; acc.lo.y += s * v.lo.y;
    acc.lo.z += s * v.lo.z; acc.lo.w += s * v.lo.w;
    acc.hi.x += s * v.hi.x; acc.hi.y += s * v.hi.y;
    acc.hi.z += s * v.hi.z; acc.hi.w += s * v.hi.w;
}
__device__ inline float nrm16(uint32 ed) {
    unsigned short u = (unsigned short)(ed >> 16);
    __half h;
    __builtin_memcpy(&h, &u, 2);
    return __half2float(h);
}
// one node's 8-half chunk (c of STRIDE uint4 per row): self+edges+bias[+relu]
// `ed` may be LDS (staged slice -> lgkmcnt) or global (fallback); inlined per
// call site so LLVM infers the address space. Proven 4-wide batching.
template <int STRIDE, bool RELU>
__device__ inline f8 gather4(const uint4* __restrict__ Pv,
                             const uint32* ed, int jb, int je,
                             const float* __restrict__ dinv,
                             const float* __restrict__ bias,
                             int node, int c) {
    float s = dinv[node];
    s *= s;
    f8 acc = cvt8(Pv[(size_t)node * STRIDE + c]);
    acc.lo.x *= s; acc.lo.y *= s; acc.lo.z *= s; acc.lo.w *= s;
    acc.hi.x *= s; acc.hi.y *= s; acc.hi.z *= s; acc.hi.w *= s;
    f8 acc2 = {make_float4(0, 0, 0, 0), make_float4(0, 0, 0, 0)};
    int j = jb;
    for (; j + 4 <= je; j += 4) {
        uint32 e0 = ed[j + 0];
        uint32 e1 = ed[j + 1];
        uint32 e2 = ed[j + 2];
        uint32 e3 = ed[j + 3];
        uint4 u0 = Pv[(size_t)(e0 & 0xffffu) * STRIDE + c];
        uint4 u1 = Pv[(size_t)(e1 & 0xffffu) * STRIDE + c];
        uint4 u2 = Pv[(size_t)(e2 & 0xffffu) * STRIDE + c];
        uint4 u3 = Pv[(size_t)(e3 & 0xffffu) * STRIDE + c];
        fma8(acc,  nrm16(e0), cvt8(u0));
        fma8(acc2, nrm16(e1), cvt8(u1));
        fma8(acc,  nrm16(e2), cvt8(u2));
        fma8(acc2, nrm16(e3), cvt8(u3));
    }
    for (; j < je; ++j) {
        uint32 ed0 = ed[j];
        fma8(acc, nrm16(ed0), cvt8(Pv[(size_t)(ed0 & 0xffffu) * STRIDE + c]));
    }
    const float4* bv = reinterpret_cast<const float4*>(bias);
    float4 b0 = bv[c * 2], b1 = bv[c * 2 + 1];
    acc.lo.x += acc2.lo.x + b0.x; acc.lo.y += acc2.lo.y + b0.y;
    acc.lo.z += acc2.lo.z + b0.z; acc.lo.w += acc2.lo.w + b0.w;
    acc.hi.x += acc2.hi.x + b1.x; acc.hi.y += acc2.hi.y + b1.y;
    acc.hi.z += acc2.hi.z + b1.z; acc.hi.w += acc2.hi.w + b1.w;
    if (RELU) {
        acc.lo.x = fmaxf(acc.lo.x, 0.f); acc.lo.y = fmaxf(acc.lo.y, 0.f);
        acc.lo.z = fmaxf(acc.lo.z, 0.f); acc.lo.w = fmaxf(acc.lo.w, 0.f);
        acc.hi.x = fmaxf(acc.hi.x, 0.f); acc.hi.y = fmaxf(acc.hi.y, 0.f);
        acc.hi.z = fmaxf(acc.hi.z, 0.f); acc.hi.w = fmaxf(acc.hi.w, 0.f);
    }
    return acc;
}
__device__ inline uint4 pack8(const f8& a) {
    __half2 h0 = __floats2half2_rn(a.lo.x, a.lo.y);
    __half2 h1 = __floats2half2_rn(a.lo.z, a.lo.w);
    __half2 h2 = __floats2half2_rn(a.hi.x, a.hi.y);
    __half2 h3 = __floats2half2_rn(a.hi.z, a.hi.w);
    uint4 o;
    o.x = *reinterpret_cast<uint32*>(&h0);
    o.y = *reinterpret_cast<uint32*>(&h1);
    o.z = *reinterpret_cast<uint32*>(&h2);
    o.w = *reinterpret_cast<uint32*>(&h3);
    return o;
}

// ---------------- layer-0 GEMM: P0[m][n] = sum_k x_f32[m][k] W[n][k] -------
template <int NT>
__global__ __launch_bounds__(256) void k_gemm0(const float* __restrict__ A,
                                               const __half* __restrict__ W,
                                               __half* __restrict__ C, int M) {
    const int N = NT * 16;
    const int tid = threadIdx.x;
    const int wave = tid >> 6;
    const int lane = tid & 63;
    const int lm = lane & 15;
    const int quad = lane >> 4;
    const int row = blockIdx.x * 64 + wave * 16 + lm;
    const bool av = row < M;

    floatx4 acc[NT] = {};
#pragma unroll
    for (int kc = 0; kc < 4; ++kc) {
        const int kk = kc * 32 + quad * 8;
        half8 a = {};
        if (av) {
            float4 f0 = *reinterpret_cast<const float4*>(A + (size_t)row * 128 + kk);
            float4 f1 = *reinterpret_cast<const float4*>(A + (size_t)row * 128 + kk + 4);
            a[0] = (_Float16)f0.x; a[1] = (_Float16)f0.y;
            a[2] = (_Float16)f0.z; a[3] = (_Float16)f0.w;
            a[4] = (_Float16)f1.x; a[5] = (_Float16)f1.y;
            a[6] = (_Float16)f1.z; a[7] = (_Float16)f1.w;
        }
#pragma unroll
        for (int ct = 0; ct < NT; ++ct) {
            half8 b = *reinterpret_cast<const half8*>(W + (size_t)(ct * 16 + lm) * 128 + kk);
            acc[ct] = __builtin_amdgcn_mfma_f32_16x16x32_f16(a, b, acc[ct], 0, 0, 0);
        }
    }
    const int rbase = blockIdx.x * 64 + wave * 16 + quad * 4;
#pragma unroll
    for (int reg = 0; reg < 4; ++reg) {
        int r = rbase + reg;
        if (r < M) {
#pragma unroll
            for (int ct = 0; ct < NT; ++ct)
                C[(size_t)r * N + ct * 16 + lm] = __float2half(acc[ct][reg]);
        }
    }
}

// ---------------- barrier-free fused gather+GEMM ---------------------------
// Block = 128 thr = 2 autonomous waves. Wave w: stage its 16 nodes' edge
// slice into LDS (coalesced, cap EDCAP, global fallback), gather its 16
// nodes into its own 4KB LDS slice (relu(gather(P)+bias), fp16, XOR-swizzled
// groups), then MFMA those 16 rows vs W (L2). NO __syncthreads — wave-
// internal LDS ordering (same-wave ds_write -> ds_read via lgkmcnt).
template <int NT>
__global__ __launch_bounds__(128) void k_gg(const __half* __restrict__ P,
                                            const int* __restrict__ offs,
                                            const uint32* __restrict__ edata,
                                            const float* __restrict__ dinv,
                                            const float* __restrict__ bias,
                                            const __half* __restrict__ W,
                                            __half* __restrict__ C, int n) {
    __shared__ __align__(16) __half Hs[2][16 * 128];  // 8 KB, 4KB per wave
    __shared__ uint32 Ed[2][EDCAP];                   // 8 KB, 4KB per wave
    const int N = NT * 16;
    const int tid = threadIdx.x;
    const int wave = tid >> 6;
    const int lane = tid & 63;
    const uint4* Pv = reinterpret_cast<const uint4*>(P);
    const int c = lane & 15;      // half-group 0..15 (8 halves each)
    const int u = lane >> 4;      // 0..3
    const int nbase = blockIdx.x * 32 + wave * 16;
    if (nbase >= n) return;       // whole wave out of range
    __half* hs = Hs[wave];
    uint32* ew = Ed[wave];

    // ---- stage this wave's edge slice into LDS (coalesced)
    const int nend = min(nbase + 16, n);
    const int t0 = offs[nbase];
    const int total = offs[nend] - t0;
    const bool fits = (total <= EDCAP);
    if (fits) {
        for (int k = lane; k < total; k += 64)
            ew[k] = edata[t0 + k];
    }
    // no barrier: same-wave ds_write/ds_read ordering via lgkmcnt

#pragma unroll 1
    for (int sub = 0; sub < 4; ++sub) {
        const int lrow = sub * 4 + u;
        const int node = nbase + lrow;
        f8 acc = {make_float4(0, 0, 0, 0), make_float4(0, 0, 0, 0)};
        if (node < n) {
            const int j0 = offs[node];
            const int j1 = offs[node + 1];
            if (fits)
                acc = gather4<16, true>(Pv, ew, j0 - t0, j1 - t0, dinv, bias, node, c);
            else
                acc = gather4<16, true>(Pv, edata, j0, j1, dinv, bias, node, c);
        }
        *reinterpret_cast<uint4*>(&hs[lrow * 128 + ((c ^ (lrow & 7)) << 3)]) =
            pack8(acc);
    }
    // no barrier: same wave wrote all 16 rows it reads below (lgkmcnt order)

    const int lm = lane & 15;
    const int quad = lane >> 4;
    floatx4 acc[NT] = {};
#pragma unroll
    for (int kc = 0; kc < 4; ++kc) {
        const int g = kc * 4 + quad;
        half8 a = *reinterpret_cast<const half8*>(
            &hs[lm * 128 + ((g ^ (lm & 7)) << 3)]);
        const int kk = g << 3;
#pragma unroll
        for (int ct = 0; ct < NT; ++ct) {
            half8 b = *reinterpret_cast<const half8*>(
                W + (size_t)(ct * 16 + lm) * 128 + kk);
            acc[ct] = __builtin_amdgcn_mfma_f32_16x16x32_f16(a, b, acc[ct], 0, 0, 0);
        }
    }
    const int rbase = nbase + quad * 4;
#pragma unroll
    for (int reg = 0; reg < 4; ++reg) {
        int r = rbase + reg;
        if (r < n) {
#pragma unroll
            for (int ct = 0; ct < NT; ++ct)
                C[(size_t)r * N + ct * 16 + lm] = __float2half(acc[ct][reg]);
        }
    }
}

// ---------------- final gather (D=64, fp32 out, no relu) -------------------
// 256 thr = 4 autonomous waves; 8 nodes/wave, 8 lanes/node. Wave stages its
// edge slice into LDS (cap EDCAP2, global fallback); 4-wide batches.
// No __syncthreads (wave-internal LDS ordering via lgkmcnt).
__global__ __launch_bounds__(256) void k_gather_out(const __half* __restrict__ P,
                                                    const int* __restrict__ offs,
                                                    const uint32* __restrict__ edata,
                                                    const float* __restrict__ dinv,
                                                    const float* __restrict__ bias,
                                                    float* __restrict__ out, int n) {
    __shared__ uint32 Ed[4][EDCAP2];   // 8 KB
    const int tid = threadIdx.x;
    const int wave = tid >> 6;
    const int lane = tid & 63;
    const int c = lane & 7;            // chunk 0..7 (8 halves each, D=64)
    const int u = lane >> 3;           // node row 0..7
    const int nbase = blockIdx.x * 32 + wave * 8;
    if (nbase >= n) return;
    const uint4* Pv = reinterpret_cast<const uint4*>(P);
    uint32* ew = Ed[wave];

    const int nend = min(nbase + 8, n);
    const int t0 = offs[nbase];
    const int total = offs[nend] - t0;
    const bool fits = (total <= EDCAP2);
    if (fits) {
        for (int k = lane; k < total; k += 64)
            ew[k] = edata[t0 + k];
    }

    const int node = nbase + u;
    if (node >= n) return;
    const int j0 = offs[node];
    const int j1 = offs[node + 1];
    f8 acc;
    if (fits)
        acc = gather4<8, false>(Pv, ew, j0 - t0, j1 - t0, dinv, bias, node, c);
    else
        acc = gather4<8, false>(Pv, edata, j0, j1, dinv, bias, node, c);

    floatx4* O = reinterpret_cast<floatx4*>(out);
    floatx4 lo = {acc.lo.x, acc.lo.y, acc.lo.z, acc.lo.w};
    floatx4 hi = {acc.hi.x, acc.hi.y, acc.hi.z, acc.hi.w};
    __builtin_nontemporal_store(lo, O + (size_t)node * 16 + c * 2);
    __builtin_nontemporal_store(hi, O + (size_t)node * 16 + c * 2 + 1);
}

extern "C" void kernel_launch(void* const* d_in, const int* in_sizes, int n_in,
                              void* d_out, int out_size, void* d_ws, size_t ws_size,
                              hipStream_t stream) {
    const float* x  = (const float*)d_in[0];
    const int*   ei = (const int*)d_in[1];   // [2][E] int32
    const float* W0 = (const float*)d_in[2];
    const float* b0 = (const float*)d_in[3];
    const float* W1 = (const float*)d_in[4];
    const float* b1 = (const float*)d_in[5];
    const float* W2 = (const float*)d_in[6];
    const float* b2 = (const float*)d_in[7];
    float* out = (float*)d_out;

    const int n = in_sizes[0] / 128;   // 50000
    const int E = in_sizes[1] / 2;     // 800000
    const int NBLK = (n + 255) / 256;  // 196

    // workspace (~30 MB):
    // deg(S) cur(S) bsum(256) bpre(256) offs(S+1) dinv(S) edata(E)
    // A fp16(12.8M) B fp16(12.8M) Wh(80K)
    int*    deg   = (int*)d_ws;
    int*    cur   = deg + SLOT;
    int*    bsum  = cur + SLOT;
    int*    bpre  = bsum + 256;
    int*    offs  = bsum + 1024;
    float*  dinv  = (float*)(offs + SLOT);
    uint32* edata = (uint32*)(dinv + SLOT);
    __half* A     = (__half*)(edata + E);
    __half* B     = A + (size_t)n * 128;
    __half* Wh    = B + (size_t)n * 128;

    // ---- weight convert + zero deg/cur (contiguous 2*SLOT ints)
    k_cvtw<<<40, 256, 0, stream>>>(W0, W1, W2, Wh, deg, 2 * SLOT);

    // ---- CSR build (global atomics, order-free edge placement)
    k_count<<<(E + 255) / 256, 256, 0, stream>>>(ei, deg, E);
    k_scan_blk<<<NBLK, 256, 0, stream>>>(deg, bsum, offs, dinv, n);
    k_scan_top<<<1, 256, 0, stream>>>(bsum, bpre, offs, NBLK, n);
    k_add<<<NBLK, 256, 0, stream>>>(offs, bpre, n);
    k_fill<<<(E + 255) / 256, 256, 0, stream>>>(ei, offs, cur, dinv, edata, E);

    const int blocks64 = (n + 63) / 64;   // 782 (gemm0)
    const int blocks32 = (n + 31) / 32;   // 1563 (fused / gather_out)

    // ---- P0 = x @ W0^T (fp32 in, fp16 out, inline convert)
    k_gemm0<8><<<blocks64, 256, 0, stream>>>(x, Wh, A, n);
    // ---- H0 = relu(gather(P0)+b0); P1 = H0 @ W1^T  (barrier-free fused)
    k_gg<8><<<blocks32, 128, 0, stream>>>(A, offs, edata, dinv, b0,
                                          Wh + 16384, B, n);
    // ---- H1 = relu(gather(P1)+b1); P2 = H1 @ W2^T  (fused, N=64)
    k_gg<4><<<blocks32, 128, 0, stream>>>(B, offs, edata, dinv, b1,
                                          Wh + 32768, A, n);
    // ---- out = gather(P2) + b2 (fp32)
    k_gather_out<<<blocks32, 256, 0, stream>>>(
        A, offs, edata, dinv, b2, out, n);
}

// Round 10
// 228.387 us; speedup vs baseline: 1.1935x; 1.1935x over previous
//
#include <hip/hip_runtime.h>
#include <hip/hip_fp16.h>

// ---------------------------------------------------------------------------
// PMLP forward: 3 x (GEMM -> symmetric-norm propagate -> bias[+relu])
// N=50000 nodes, E=800000 edges, dims 128->128->128->64, fp32 in/out.
// R2..R11: CSR gather, atomic-free build, fp16 MFMA GEMM, u8 metadata.
// R14: barrier-free fused gather+GEMM. R17: wave-staged LDS edata (248.2).
// R15/R16/R18/R19/R20 REVERTED: concurrency/batch-width/unfuse -- gather is
//      throughput-saturated on the random L2-miss/fabric path (205MB/layer
//      @ ~5TB/s = 41us = measured); fp16 256B rows are the per-edge minimum.
// R21: bp [b_quad][bin] + staged k_gather_out (241.2, best).
// R22 REVERTED: global-atomic CSR build (272.6). atomicAdd-with-return in
//      k_fill serializes placement behind L2 round-trips; extra ei pass.
// R23 (this): R21 restored + block-partitioned MEGA-KERNEL overlap of
//      independent work (same-stream kernels serialize; blocks don't):
//      F1 = cvtw(40 blocks) || hist(256 blocks)     [disjoint data]
//      F2 = merge(196)      || gemm0(782)           [partial un-aliased
//      from A so gemm0 can write A while merge reads partial].
//      gemm0's ~10us hides under merge; launches 11 -> 8.
// ---------------------------------------------------------------------------

#define NB 256          // histogram blocks / sort chunks (E/NB = 3125)
#define NBINS 50000
#define HW4 12500       // LDS words, 4 u8 bins per word
#define EDCAP 1024      // LDS edge-slice capacity per k_gg wave (avg ~272)
#define EDCAP2 512      // LDS edge-slice capacity per k_gather_out wave

typedef unsigned int uint32;
typedef unsigned char uint8;
typedef _Float16 half8 __attribute__((ext_vector_type(8)));
typedef float floatx4 __attribute__((ext_vector_type(4)));

// ---------------- F1: weight convert (blocks 0..39) || histogram (40..295) -
__global__ __launch_bounds__(256) void k_f1(const float* __restrict__ w0,
                                            const float* __restrict__ w1,
                                            const float* __restrict__ w2,
                                            __half* __restrict__ dst,
                                            const int* __restrict__ ei,
                                            uint8* __restrict__ rank,
                                            uint32* __restrict__ partial, int E) {
    __shared__ uint32 h[HW4];   // 50 KB (hist branch; reserved for all blocks)
    if (blockIdx.x < 40) {
        int i = blockIdx.x * 256 + threadIdx.x;   // quad index, 0..10239
        if (i >= 10240) return;
        const float* s;
        int off;
        if (i < 4096)      { s = w0; off = i; }
        else if (i < 8192) { s = w1; off = i - 4096; }
        else               { s = w2; off = i - 8192; }
        float4 v = reinterpret_cast<const float4*>(s)[off];
        __half2 h0 = __floats2half2_rn(v.x, v.y);
        __half2 h1 = __floats2half2_rn(v.z, v.w);
        uint2 o;
        o.x = *reinterpret_cast<uint32*>(&h0);
        o.y = *reinterpret_cast<uint32*>(&h1);
        reinterpret_cast<uint2*>(dst)[i] = o;
        return;
    }
    const int b = blockIdx.x - 40;
    const int chunk = (E + NB - 1) / NB;
    const int base = b * chunk;
    const int lim = min(base + chunk, E);
    for (int w = threadIdx.x; w < HW4; w += 256) h[w] = 0;
    __syncthreads();
    for (int e = base + threadIdx.x; e < lim; e += 256) {
        int c = ei[E + e];
        int sh = (c & 3) * 8;
        uint32 old = atomicAdd(&h[c >> 2], 1u << sh);
        rank[e] = (uint8)((old >> sh) & 0xffu);
    }
    __syncthreads();
    uint32* dstp = partial + (size_t)b * HW4;
    for (int w = threadIdx.x; w < HW4; w += 256) dstp[w] = h[w];
}

// ---------------- F2: merge (blocks 0..nblk-1) || gemm0 (nblk..) -----------
// merge: bp layout [b_quad][bin]; also block-local exclusive offs + dinv.
// gemm0: P0 = x @ W0^T (fp32 in, fp16 row-major out), 64 rows/block.
template <int NT>
__global__ __launch_bounds__(256) void k_f2(const uint32* __restrict__ partial,
                                            uint32* __restrict__ bp,
                                            int* __restrict__ bsum,
                                            int* __restrict__ offs,
                                            float* __restrict__ dinv, int n,
                                            int nblk,
                                            const float* __restrict__ A,
                                            const __half* __restrict__ W,
                                            __half* __restrict__ C, int M) {
    __shared__ int wsums[5];
    const int tid = threadIdx.x;
    if ((int)blockIdx.x < nblk) {
        const int bin = blockIdx.x * 256 + tid;
        const int lane = tid & 63;
        const int wid = tid >> 6;
        uint32 run = 0;
        if (bin < n) {
            const int word = bin >> 2;
            const int sh = (bin & 3) * 8;
#pragma unroll 4
            for (int b = 0; b < NB; b += 4) {
                uint32 c0 = (partial[(size_t)(b + 0) * HW4 + word] >> sh) & 0xffu;
                uint32 c1 = (partial[(size_t)(b + 1) * HW4 + word] >> sh) & 0xffu;
                uint32 c2 = (partial[(size_t)(b + 2) * HW4 + word] >> sh) & 0xffu;
                uint32 c3 = (partial[(size_t)(b + 3) * HW4 + word] >> sh) & 0xffu;
                uint32 p1 = run + c0, p2 = p1 + c1, p3 = p2 + c2;
                bp[(size_t)(b >> 2) * NBINS + bin] =
                    run | (p1 << 8) | (p2 << 16) | (p3 << 24);
                run = p3 + c3;
            }
            dinv[bin] = rsqrtf((float)run + 1.0f);
        }
        int s = (int)run;
#pragma unroll
        for (int off = 1; off < 64; off <<= 1) {
            int t = __shfl_up(s, off);
            if (lane >= off) s += t;
        }
        if (lane == 63) wsums[wid] = s;
        __syncthreads();
        if (tid == 0) {
            int a = 0;
            for (int w = 0; w < 4; ++w) { int t = wsums[w]; wsums[w] = a; a += t; }
            wsums[4] = a;
        }
        __syncthreads();
        if (bin < n) offs[bin] = wsums[wid] + s - (int)run;
        if (tid == 255) bsum[blockIdx.x] = wsums[4];
        return;
    }
    // ---- gemm0 branch
    const int gbid = blockIdx.x - nblk;
    const int N = NT * 16;
    const int wave = tid >> 6;
    const int lane = tid & 63;
    const int lm = lane & 15;
    const int quad = lane >> 4;
    const int row = gbid * 64 + wave * 16 + lm;
    const bool av = row < M;

    floatx4 acc[NT] = {};
#pragma unroll
    for (int kc = 0; kc < 4; ++kc) {
        const int kk = kc * 32 + quad * 8;
        half8 a = {};
        if (av) {
            float4 f0 = *reinterpret_cast<const float4*>(A + (size_t)row * 128 + kk);
            float4 f1 = *reinterpret_cast<const float4*>(A + (size_t)row * 128 + kk + 4);
            a[0] = (_Float16)f0.x; a[1] = (_Float16)f0.y;
            a[2] = (_Float16)f0.z; a[3] = (_Float16)f0.w;
            a[4] = (_Float16)f1.x; a[5] = (_Float16)f1.y;
            a[6] = (_Float16)f1.z; a[7] = (_Float16)f1.w;
        }
#pragma unroll
        for (int ct = 0; ct < NT; ++ct) {
            half8 b = *reinterpret_cast<const half8*>(W + (size_t)(ct * 16 + lm) * 128 + kk);
            acc[ct] = __builtin_amdgcn_mfma_f32_16x16x32_f16(a, b, acc[ct], 0, 0, 0);
        }
    }
    const int rbase = gbid * 64 + wave * 16 + quad * 4;
#pragma unroll
    for (int reg = 0; reg < 4; ++reg) {
        int r = rbase + reg;
        if (r < M) {
#pragma unroll
            for (int ct = 0; ct < NT; ++ct)
                C[(size_t)r * N + ct * 16 + lm] = __float2half(acc[ct][reg]);
        }
    }
}

__global__ __launch_bounds__(256) void k_scan_top(const int* __restrict__ bsum,
                                                  int* __restrict__ bpre,
                                                  int* __restrict__ offs,
                                                  int nblk, int n) {
    __shared__ int wsums[5];
    const int tid = threadIdx.x;
    const int lane = tid & 63;
    const int wid = tid >> 6;
    int v = (tid < nblk) ? bsum[tid] : 0;
    int s = v;
#pragma unroll
    for (int off = 1; off < 64; off <<= 1) {
        int t = __shfl_up(s, off);
        if (lane >= off) s += t;
    }
    if (lane == 63) wsums[wid] = s;
    __syncthreads();
    if (tid == 0) {
        int a = 0;
        for (int w = 0; w < 4; ++w) { int t = wsums[w]; wsums[w] = a; a += t; }
        wsums[4] = a;
    }
    __syncthreads();
    if (tid < nblk) bpre[tid] = wsums[wid] + s - v;
    if (tid == 0) offs[n] = wsums[4];
}

__global__ __launch_bounds__(256) void k_add(int* __restrict__ offs,
                                             const int* __restrict__ bpre, int n) {
    int bin = blockIdx.x * 256 + threadIdx.x;
    if (bin < n) offs[bin] += bpre[blockIdx.x];
}

__global__ __launch_bounds__(256) void k_fill(const int* __restrict__ ei,
                                              const int* __restrict__ offs,
                                              const uint32* __restrict__ bp,
                                              const uint8* __restrict__ rank,
                                              const float* __restrict__ dinv,
                                              uint32* __restrict__ edata, int E) {
    int e = blockIdx.x * 256 + threadIdx.x;
    if (e >= E) return;
    const int chunk = (E + NB - 1) / NB;
    int b = e / chunk;
    int r = ei[e];
    int c = ei[E + e];
    // bp[b_quad][bin]: b uniform per block -> reads live in one 200KB row
    uint32 pk = bp[(size_t)(b >> 2) * NBINS + c];
    int pref = (pk >> ((b & 3) * 8)) & 0xff;
    int pos = offs[c] + pref + (int)rank[e];
    __half h = __float2half(dinv[r] * dinv[c]);
    unsigned short hb = *reinterpret_cast<unsigned short*>(&h);
    edata[pos] = (uint32)(unsigned short)r | ((uint32)hb << 16);
}

// ---------------- gather helpers ----------------
struct f8 { float4 lo, hi; };
__device__ inline f8 cvt8(uint4 u) {
    __half2* h = reinterpret_cast<__half2*>(&u);
    float2 a = __half22float2(h[0]);
    float2 b = __half22float2(h[1]);
    float2 c = __half22float2(h[2]);
    float2 d = __half22float2(h[3]);
    f8 r;
    r.lo = make_float4(a.x, a.y, b.x, b.y);
    r.hi = make_float4(c.x, c.y, d.x, d.y);
    return r;
}
__device__ inline void fma8(f8& acc, float s, const f8& v) {
    acc.lo.x += s * v.lo.x; acc.lo.y += s * v.lo.y;
    acc.lo.z += s * v.lo.z; acc.lo.w += s * v.lo.w;
    acc.hi.x += s * v.hi.x; acc.hi.y += s * v.hi.y;
    acc.hi.z += s * v.hi.z; acc.hi.w += s * v.hi.w;
}
__device__ inline float nrm16(uint32 ed) {
    unsigned short u = (unsigned short)(ed >> 16);
    __half h;
    __builtin_memcpy(&h, &u, 2);
    return __half2float(h);
}
// one node's 8-half chunk (c of STRIDE uint4 per row): self+edges+bias[+relu]
// `ed` may be LDS (staged slice -> lgkmcnt) or global (fallback); inlined per
// call site so LLVM infers the address space. Proven 4-wide batching.
template <int STRIDE, bool RELU>
__device__ inline f8 gather4(const uint4* __restrict__ Pv,
                             const uint32* ed, int jb, int je,
                             const float* __restrict__ dinv,
                             const float* __restrict__ bias,
                             int node, int c) {
    float s = dinv[node];
    s *= s;
    f8 acc = cvt8(Pv[(size_t)node * STRIDE + c]);
    acc.lo.x *= s; acc.lo.y *= s; acc.lo.z *= s; acc.lo.w *= s;
    acc.hi.x *= s; acc.hi.y *= s; acc.hi.z *= s; acc.hi.w *= s;
    f8 acc2 = {make_float4(0, 0, 0, 0), make_float4(0, 0, 0, 0)};
    int j = jb;
    for (; j + 4 <= je; j += 4) {
        uint32 e0 = ed[j + 0];
        uint32 e1 = ed[j + 1];
        uint32 e2 = ed[j + 2];
        uint32 e3 = ed[j + 3];
        uint4 u0 = Pv[(size_t)(e0 & 0xffffu) * STRIDE + c];
        uint4 u1 = Pv[(size_t)(e1 & 0xffffu) * STRIDE + c];
        uint4 u2 = Pv[(size_t)(e2 & 0xffffu) * STRIDE + c];
        uint4 u3 = Pv[(size_t)(e3 & 0xffffu) * STRIDE + c];
        fma8(acc,  nrm16(e0), cvt8(u0));
        fma8(acc2, nrm16(e1), cvt8(u1));
        fma8(acc,  nrm16(e2), cvt8(u2));
        fma8(acc2, nrm16(e3), cvt8(u3));
    }
    for (; j < je; ++j) {
        uint32 ed0 = ed[j];
        fma8(acc, nrm16(ed0), cvt8(Pv[(size_t)(ed0 & 0xffffu) * STRIDE + c]));
    }
    const float4* bv = reinterpret_cast<const float4*>(bias);
    float4 b0 = bv[c * 2], b1 = bv[c * 2 + 1];
    acc.lo.x += acc2.lo.x + b0.x; acc.lo.y += acc2.lo.y + b0.y;
    acc.lo.z += acc2.lo.z + b0.z; acc.lo.w += acc2.lo.w + b0.w;
    acc.hi.x += acc2.hi.x + b1.x; acc.hi.y += acc2.hi.y + b1.y;
    acc.hi.z += acc2.hi.z + b1.z; acc.hi.w += acc2.hi.w + b1.w;
    if (RELU) {
        acc.lo.x = fmaxf(acc.lo.x, 0.f); acc.lo.y = fmaxf(acc.lo.y, 0.f);
        acc.lo.z = fmaxf(acc.lo.z, 0.f); acc.lo.w = fmaxf(acc.lo.w, 0.f);
        acc.hi.x = fmaxf(acc.hi.x, 0.f); acc.hi.y = fmaxf(acc.hi.y, 0.f);
        acc.hi.z = fmaxf(acc.hi.z, 0.f); acc.hi.w = fmaxf(acc.hi.w, 0.f);
    }
    return acc;
}
__device__ inline uint4 pack8(const f8& a) {
    __half2 h0 = __floats2half2_rn(a.lo.x, a.lo.y);
    __half2 h1 = __floats2half2_rn(a.lo.z, a.lo.w);
    __half2 h2 = __floats2half2_rn(a.hi.x, a.hi.y);
    __half2 h3 = __floats2half2_rn(a.hi.z, a.hi.w);
    uint4 o;
    o.x = *reinterpret_cast<uint32*>(&h0);
    o.y = *reinterpret_cast<uint32*>(&h1);
    o.z = *reinterpret_cast<uint32*>(&h2);
    o.w = *reinterpret_cast<uint32*>(&h3);
    return o;
}

// ---------------- barrier-free fused gather+GEMM ---------------------------
// Block = 128 thr = 2 autonomous waves. Wave w: stage its 16 nodes' edge
// slice into LDS (coalesced, cap EDCAP, global fallback), gather its 16
// nodes into its own 4KB LDS slice (relu(gather(P)+bias), fp16, XOR-swizzled
// groups), then MFMA those 16 rows vs W (L2). NO __syncthreads — wave-
// internal LDS ordering (same-wave ds_write -> ds_read via lgkmcnt).
template <int NT>
__global__ __launch_bounds__(128) void k_gg(const __half* __restrict__ P,
                                            const int* __restrict__ offs,
                                            const uint32* __restrict__ edata,
                                            const float* __restrict__ dinv,
                                            const float* __restrict__ bias,
                                            const __half* __restrict__ W,
                                            __half* __restrict__ C, int n) {
    __shared__ __align__(16) __half Hs[2][16 * 128];  // 8 KB, 4KB per wave
    __shared__ uint32 Ed[2][EDCAP];                   // 8 KB, 4KB per wave
    const int N = NT * 16;
    const int tid = threadIdx.x;
    const int wave = tid >> 6;
    const int lane = tid & 63;
    const uint4* Pv = reinterpret_cast<const uint4*>(P);
    const int c = lane & 15;      // half-group 0..15 (8 halves each)
    const int u = lane >> 4;      // 0..3
    const int nbase = blockIdx.x * 32 + wave * 16;
    if (nbase >= n) return;       // whole wave out of range
    __half* hs = Hs[wave];
    uint32* ew = Ed[wave];

    // ---- stage this wave's edge slice into LDS (coalesced)
    const int nend = min(nbase + 16, n);
    const int t0 = offs[nbase];
    const int total = offs[nend] - t0;
    const bool fits = (total <= EDCAP);
    if (fits) {
        for (int k = lane; k < total; k += 64)
            ew[k] = edata[t0 + k];
    }
    // no barrier: same-wave ds_write/ds_read ordering via lgkmcnt

#pragma unroll 1
    for (int sub = 0; sub < 4; ++sub) {
        const int lrow = sub * 4 + u;
        const int node = nbase + lrow;
        f8 acc = {make_float4(0, 0, 0, 0), make_float4(0, 0, 0, 0)};
        if (node < n) {
            const int j0 = offs[node];
            const int j1 = offs[node + 1];
            if (fits)
                acc = gather4<16, true>(Pv, ew, j0 - t0, j1 - t0, dinv, bias, node, c);
            else
                acc = gather4<16, true>(Pv, edata, j0, j1, dinv, bias, node, c);
        }
        *reinterpret_cast<uint4*>(&hs[lrow * 128 + ((c ^ (lrow & 7)) << 3)]) =
            pack8(acc);
    }
    // no barrier: same wave wrote all 16 rows it reads below (lgkmcnt order)

    const int lm = lane & 15;
    const int quad = lane >> 4;
    floatx4 acc[NT] = {};
#pragma unroll
    for (int kc = 0; kc < 4; ++kc) {
        const int g = kc * 4 + quad;
        half8 a = *reinterpret_cast<const half8*>(
            &hs[lm * 128 + ((g ^ (lm & 7)) << 3)]);
        const int kk = g << 3;
#pragma unroll
        for (int ct = 0; ct < NT; ++ct) {
            half8 b = *reinterpret_cast<const half8*>(
                W + (size_t)(ct * 16 + lm) * 128 + kk);
            acc[ct] = __builtin_amdgcn_mfma_f32_16x16x32_f16(a, b, acc[ct], 0, 0, 0);
        }
    }
    const int rbase = nbase + quad * 4;
#pragma unroll
    for (int reg = 0; reg < 4; ++reg) {
        int r = rbase + reg;
        if (r < n) {
#pragma unroll
            for (int ct = 0; ct < NT; ++ct)
                C[(size_t)r * N + ct * 16 + lm] = __float2half(acc[ct][reg]);
        }
    }
}

// ---------------- final gather (D=64, fp32 out, no relu) -------------------
// 256 thr = 4 autonomous waves; 8 nodes/wave, 8 lanes/node. Wave stages its
// edge slice into LDS (cap EDCAP2, global fallback); 4-wide batches.
// No __syncthreads (wave-internal LDS ordering via lgkmcnt).
__global__ __launch_bounds__(256) void k_gather_out(const __half* __restrict__ P,
                                                    const int* __restrict__ offs,
                                                    const uint32* __restrict__ edata,
                                                    const float* __restrict__ dinv,
                                                    const float* __restrict__ bias,
                                                    float* __restrict__ out, int n) {
    __shared__ uint32 Ed[4][EDCAP2];   // 8 KB
    const int tid = threadIdx.x;
    const int wave = tid >> 6;
    const int lane = tid & 63;
    const int c = lane & 7;            // chunk 0..7 (8 halves each, D=64)
    const int u = lane >> 3;           // node row 0..7
    const int nbase = blockIdx.x * 32 + wave * 8;
    if (nbase >= n) return;
    const uint4* Pv = reinterpret_cast<const uint4*>(P);
    uint32* ew = Ed[wave];

    const int nend = min(nbase + 8, n);
    const int t0 = offs[nbase];
    const int total = offs[nend] - t0;
    const bool fits = (total <= EDCAP2);
    if (fits) {
        for (int k = lane; k < total; k += 64)
            ew[k] = edata[t0 + k];
    }

    const int node = nbase + u;
    if (node >= n) return;
    const int j0 = offs[node];
    const int j1 = offs[node + 1];
    f8 acc;
    if (fits)
        acc = gather4<8, false>(Pv, ew, j0 - t0, j1 - t0, dinv, bias, node, c);
    else
        acc = gather4<8, false>(Pv, edata, j0, j1, dinv, bias, node, c);

    floatx4* O = reinterpret_cast<floatx4*>(out);
    floatx4 lo = {acc.lo.x, acc.lo.y, acc.lo.z, acc.lo.w};
    floatx4 hi = {acc.hi.x, acc.hi.y, acc.hi.z, acc.hi.w};
    __builtin_nontemporal_store(lo, O + (size_t)node * 16 + c * 2);
    __builtin_nontemporal_store(hi, O + (size_t)node * 16 + c * 2 + 1);
}

extern "C" void kernel_launch(void* const* d_in, const int* in_sizes, int n_in,
                              void* d_out, int out_size, void* d_ws, size_t ws_size,
                              hipStream_t stream) {
    const float* x  = (const float*)d_in[0];
    const int*   ei = (const int*)d_in[1];   // [2][E] int32
    const float* W0 = (const float*)d_in[2];
    const float* b0 = (const float*)d_in[3];
    const float* W1 = (const float*)d_in[4];
    const float* b1 = (const float*)d_in[5];
    const float* W2 = (const float*)d_in[6];
    const float* b2 = (const float*)d_in[7];
    float* out = (float*)d_out;

    const int n = in_sizes[0] / 128;   // 50000
    const int E = in_sizes[1] / 2;     // 800000
    const int NBLK = (n + 255) / 256;  // 196

    // workspace (~56 MB, ws is ~268MB):
    // bp(12.8M, [b_quad][bin]) rank(0.8M) bsum/bpre offs dinv edata(3.2M)
    // A fp16(12.8M) B fp16(12.8M) Wh(80K) partial(12.8M, own space so
    // gemm0 (writes A) can overlap merge (reads partial) inside F2)
    const int S = 51200;
    uint32* bp    = (uint32*)d_ws;
    uint8*  rank  = (uint8*)(bp + (size_t)NBINS * (NB / 4));
    int*    bsum  = (int*)(rank + E);
    int*    bpre  = bsum + 256;
    int*    offs  = bsum + S;
    float*  dinv  = (float*)(offs + S);
    uint32* edata = (uint32*)(dinv + S);
    __half* A     = (__half*)(edata + E);
    __half* B     = A + (size_t)n * 128;
    __half* Wh    = B + (size_t)n * 128;
    uint32* partial = (uint32*)(Wh + 40960);   // own 12.8MB

    const int blocks64 = (n + 63) / 64;   // 782 (gemm0)
    const int blocks32 = (n + 31) / 32;   // 1563 (fused / gather_out)

    // ---- F1: weight convert || histogram (disjoint data)
    k_f1<<<40 + NB, 256, 0, stream>>>(W0, W1, W2, Wh, ei, rank, partial, E);
    // ---- F2: merge || P0 = x @ W0^T (gemm0 hides under merge)
    k_f2<8><<<NBLK + blocks64, 256, 0, stream>>>(partial, bp, bsum, offs,
                                                 dinv, n, NBLK, x, Wh, A, n);
    k_scan_top<<<1, 256, 0, stream>>>(bsum, bpre, offs, NBLK, n);
    k_add<<<NBLK, 256, 0, stream>>>(offs, bpre, n);
    k_fill<<<(E + 255) / 256, 256, 0, stream>>>(ei, offs, bp, rank, dinv, edata, E);

    // ---- H0 = relu(gather(P0)+b0); P1 = H0 @ W1^T  (barrier-free fused)
    k_gg<8><<<blocks32, 128, 0, stream>>>(A, offs, edata, dinv, b0,
                                          Wh + 16384, B, n);
    // ---- H1 = relu(gather(P1)+b1); P2 = H1 @ W2^T  (fused, N=64)
    k_gg<4><<<blocks32, 128, 0, stream>>>(B, offs, edata, dinv, b1,
                                          Wh + 32768, A, n);
    // ---- out = gather(P2) + b2 (fp32)
    k_gather_out<<<blocks32, 256, 0, stream>>>(
        A, offs, edata, dinv, b2, out, n);
}